// Round 3
// baseline (298.965 us; speedup 1.0000x reference)
//
#include <hip/hip_runtime.h>
#include <hip/hip_bf16.h>
#include <stdint.h>

#define N_BATCH 16384
#define D_IN    2048
#define E_OUT   512
#define K_CONV  1537   // D_IN - E_OUT + 1
#define EPS_N   1e-12f
#define BKD     64     // K-depth per iteration
#define N_ITERS 26     // 1664 / BKD (band-limited K range, uniform for all blocks)

typedef unsigned short u16;
typedef __bf16 bf16x8 __attribute__((ext_vector_type(8)));
typedef float  f32x4  __attribute__((ext_vector_type(4)));

__device__ __forceinline__ unsigned f2bf_sw(float f) {
    union { float f; unsigned int u; } a; a.f = f;
    unsigned int r = a.u + 0x7FFFu + ((a.u >> 16) & 1u);   // RNE
    return r >> 16;
}

__device__ __forceinline__ unsigned pk_bf16(float a, float b) {
#if __has_builtin(__builtin_amdgcn_cvt_pk_bf16_f32)
    typedef __bf16 bf16x2 __attribute__((ext_vector_type(2)));
    bf16x2 r = __builtin_amdgcn_cvt_pk_bf16_f32(a, b);     // HW RNE, 1 inst / 2 elems
    union { bf16x2 v; unsigned u; } c; c.v = r;
    return c.u;
#else
    return f2bf_sw(a) | (f2bf_sw(b) << 16);
#endif
}

__device__ __forceinline__ bf16x8 cvt8(f32x4 lo, f32x4 hi) {
    union { uint4 u; bf16x8 v; } r;
    r.u.x = pk_bf16(lo[0], lo[1]);
    r.u.y = pk_bf16(lo[2], lo[3]);
    r.u.z = pk_bf16(hi[0], hi[1]);
    r.u.w = pk_bf16(hi[2], hi[3]);
    return r.v;
}

// ---------------- densify banded W into bf16 (E_OUT x D_IN) ----------------
__global__ __launch_bounds__(256) void prep_w_kernel(const float* __restrict__ w,
                                                     u16* __restrict__ wb) {
    int idx = blockIdx.x * 256 + threadIdx.x;
    int e = idx >> 11;
    int d = idx & (D_IN - 1);
    int k = d - e;
    float v = (k >= 0 && k < K_CONV) ? w[e * K_CONV + k] : 0.0f;
    wb[idx] = (u16)f2bf_sw(v);
}

// ---------------- fused cvt + bf16 MFMA GEMM + bias + row-ssq ----------------
// R2 diagnosis: LDS port ~90% busy (8 waves x 24 b128 ops x ~11 cyc ~ wall/iter)
// with A paying global->reg->pack->ds_write->ds_read->MFMA. THIS round: A skips
// LDS entirely. Each wave loads its own MFMA A-fragments straight from global
// (per-instr-pair: 16 rows x 128B contiguous, fully coalesced; waves sharing wm
// duplicate the read -> L2 hit, HBM unchanged), holds them in f32 regs for one
// full iteration (issued after COMPUTE -> max aging vs HBM latency), cvt_pk's
// to bf16 right before use. LDS now carries only B (glds, double-buffered).
// Barrier = s_waitcnt vmcnt(16) (drain 4 B-glds, keep 16 A-loads in flight)
// + raw s_barrier. Numerics identical to previous rounds.
__global__ __launch_bounds__(256, 2) void gemm_fused_kernel(const float* __restrict__ A,
                                                            const u16* __restrict__ B,
                                                            const float* __restrict__ bias,
                                                            float* __restrict__ C,
                                                            float* __restrict__ Psq) {
    __shared__ __align__(16) u16 Bs[2][128][64];   // 2 x 16 KB, row-major + swizzle
    __shared__ float ssq_lds[128];

    const int tid  = threadIdx.x;
    const int lane = tid & 63;
    const int wave = tid >> 6;
    const int quad = lane >> 4;
    const int r16  = lane & 15;
    const int wm   = (wave >> 1) << 6;
    const int wn   = (wave & 1) << 6;

    // XCD-aware decode: 4 n-tiles of one m-row adjacent on one XCD (L%8 = xcd)
    const int L     = blockIdx.x;        // [0, 512)
    const int xcd   = L & 7;
    const int s     = L >> 3;            // [0, 64)
    const int n_idx = s & 3;
    const int m_idx = (s >> 2) * 8 + xcd;

    const int m0 = m_idx * 128;
    const int n0 = n_idx * 128;
    const int k_begin = n0;              // band-limited K: [n0, n0+1664)

    // ---- B staging map (glds): 1024 16B-chunks, 4 per thread, lane-linear dest,
    //      pre-swizzled global source octet (sw = oct ^ row&7)
    const u16* bgN[4];
    u16* bsP[2][4];
#pragma unroll
    for (int c = 0; c < 4; ++c) {
        const int li  = tid + 256 * c;
        const int row = li >> 3;         // [0, 128)
        const int oct = li & 7;          // [0, 8)
        const int sw  = oct ^ (row & 7);
        bgN[c] = B + (size_t)(n0 + row) * D_IN + k_begin + sw * 8;
        bsP[0][c] = &Bs[0][0][0] + li * 8;
        bsP[1][c] = &Bs[1][0][0] + li * 8;
    }

    // ---- B fragment read bases (swizzled); +t4*1024 walks rows, +8192 = buf1
    const int sq = r16 & 7;
    const u16* bF[2];
    bF[0] = &Bs[0][wn + r16][((quad    ) ^ sq) * 8];
    bF[1] = &Bs[0][wn + r16][((quad + 4) ^ sq) * 8];

    // ---- A direct fragment pointers: lane (r16,quad) covers
    //      row = m0+wm+t4*16+r16, cols k_begin+it*64 + kk*32 + quad*8 + [0,8)
    const float* agt[4];
#pragma unroll
    for (int t4 = 0; t4 < 4; ++t4)
        agt[t4] = A + (size_t)(m0 + wm + t4 * 16 + r16) * D_IN + k_begin + quad * 8;

    f32x4  acc[4][4] = {};
    f32x4  arF[16];                      // in-flight f32 A (next tile)
    bf16x8 abf[8];                       // cvt'd A (current tile): abf[kk*4+t4]

#define LOAD_AF()                                               \
    _Pragma("unroll")                                           \
    for (int t4 = 0; t4 < 4; ++t4) {                            \
        _Pragma("unroll")                                       \
        for (int kk = 0; kk < 2; ++kk) {                        \
            arF[t4*4+kk*2]   = *(const f32x4*)(agt[t4] + kk*32);     \
            arF[t4*4+kk*2+1] = *(const f32x4*)(agt[t4] + kk*32 + 4); \
        }                                                       \
        agt[t4] += BKD;                                         \
    }

#define CVT()                                                   \
    _Pragma("unroll")                                           \
    for (int t4 = 0; t4 < 4; ++t4)                              \
        _Pragma("unroll")                                       \
        for (int kk = 0; kk < 2; ++kk)                          \
            abf[kk*4+t4] = cvt8(arF[t4*4+kk*2], arF[t4*4+kk*2+1]);

#define GLDS_B(buf)                                             \
    _Pragma("unroll")                                           \
    for (int c = 0; c < 4; ++c)                                 \
        __builtin_amdgcn_global_load_lds(                       \
            (const __attribute__((address_space(1))) void*)bgN[c], \
            (__attribute__((address_space(3))) void*)bsP[buf][c], 16, 0, 0);

#define BUMP_B()                                                \
    _Pragma("unroll")                                           \
    for (int c = 0; c < 4; ++c) bgN[c] += BKD;

#define COMPUTE(buf)                                            \
    _Pragma("unroll")                                           \
    for (int kk = 0; kk < 2; ++kk) {                            \
        bf16x8 bf[4];                                           \
        _Pragma("unroll")                                       \
        for (int t4 = 0; t4 < 4; ++t4)                          \
            bf[t4] = *(const bf16x8*)(bF[kk] + (buf) * 8192 + t4 * 1024); \
        _Pragma("unroll")                                       \
        for (int i = 0; i < 4; ++i)                             \
            _Pragma("unroll")                                   \
            for (int j = 0; j < 4; ++j)                         \
                acc[i][j] = __builtin_amdgcn_mfma_f32_16x16x32_bf16(abf[kk*4+i], bf[j], acc[i][j], 0, 0, 0); \
    }

// drain this iter's 4 B-glds (oldest VMEM), keep the 16 A-loads in flight
#define BAR_FAST()                                              \
    __builtin_amdgcn_sched_barrier(0);                          \
    asm volatile("s_waitcnt vmcnt(16)");                        \
    __builtin_amdgcn_sched_barrier(0);                          \
    __builtin_amdgcn_s_barrier();                               \
    __builtin_amdgcn_sched_barrier(0);

    // ---- prologue ----
    {
        LOAD_AF();                       // tile 0 -> arF
        GLDS_B(0);                       // B tile 0 -> buf0
        BUMP_B();
        CVT();                           // abf = tile 0 (one-time HBM-latency stall)
        LOAD_AF();                       // tile 1 -> arF (in flight)
        BAR_FAST();                      // drains glds0; A-loads stay in flight
    }

    // ---- main loop: 12 double-iterations, tiles 0..23 ----
    for (int p = 0; p < 12; ++p) {
        // even iter it=2p: compute tile it from buf0; stage it+1 -> buf1
        {
            GLDS_B(1);
            BUMP_B();
            COMPUTE(0);                  // uses abf (tile it)
            CVT();                       // abf = tile it+1 (arF aged ~1 iter)
            LOAD_AF();                   // tile it+2 -> arF
            BAR_FAST();
        }
        // odd iter it=2p+1: compute tile it from buf1; stage it+1 -> buf0
        {
            GLDS_B(0);
            BUMP_B();
            COMPUTE(1);
            CVT();                       // abf = tile it+1
            LOAD_AF();                   // tile it+2
            BAR_FAST();
        }
    }

    // ---- peeled tail: tiles 24, 25 (arF holds tile 25's f32 from it=23) ----
    {
        GLDS_B(1);                       // B tile 25 -> buf1
        COMPUTE(0);                      // tile 24
        CVT();                           // abf = tile 25
        __syncthreads();                 // full drain (tail — correctness first)
        COMPUTE(1);                      // tile 25
    }

    // ---- epilogue: bias add, store pre-norm C, per-row sum-of-squares ----
    __syncthreads();
    if (tid < 128) ssq_lds[tid] = 0.0f;

    float ssq_t[16];
#pragma unroll
    for (int t = 0; t < 16; ++t) ssq_t[t] = 0.0f;

#pragma unroll
    for (int j = 0; j < 4; ++j) {
        const int col = n0 + wn + j * 16 + r16;
        const float bv = bias[col];
#pragma unroll
        for (int i = 0; i < 4; ++i) {
            const int rowb = m0 + wm + i * 16 + quad * 4;
#pragma unroll
            for (int rg = 0; rg < 4; ++rg) {
                const float v = acc[i][j][rg] + bv;
                C[(size_t)(rowb + rg) * E_OUT + col] = v;
                ssq_t[i * 4 + rg] += v * v;
            }
        }
    }

#pragma unroll
    for (int off = 1; off <= 8; off <<= 1)
#pragma unroll
        for (int t = 0; t < 16; ++t)
            ssq_t[t] += __shfl_xor(ssq_t[t], off, 64);

    __syncthreads();
    if (r16 == 0) {
#pragma unroll
        for (int i = 0; i < 4; ++i)
#pragma unroll
            for (int rg = 0; rg < 4; ++rg)
                atomicAdd(&ssq_lds[wm + i * 16 + quad * 4 + rg], ssq_t[i * 4 + rg]);
    }
    __syncthreads();
    if (tid < 128)
        Psq[(size_t)n_idx * N_BATCH + m0 + tid] = ssq_lds[tid];
}

// ---------------- lite norm: out *= 1/max(sqrt(sum Psq), eps) ----------------
__global__ __launch_bounds__(256) void norm_kernel(float* __restrict__ out,
                                                   const float* __restrict__ Psq) {
    const int wave = threadIdx.x >> 6;
    const int lane = threadIdx.x & 63;
    const size_t row = (size_t)blockIdx.x * 4 + wave;
    const float ss = Psq[row] + Psq[N_BATCH + row] +
                     Psq[2 * N_BATCH + row] + Psq[3 * N_BATCH + row];
    const float inv = 1.0f / fmaxf(sqrtf(ss), EPS_N);
    float4* p = (float4*)(out + row * E_OUT);
    float4 v0 = p[lane * 2];
    float4 v1 = p[lane * 2 + 1];
    v0.x *= inv; v0.y *= inv; v0.z *= inv; v0.w *= inv;
    v1.x *= inv; v1.y *= inv; v1.z *= inv; v1.w *= inv;
    p[lane * 2] = v0;
    p[lane * 2 + 1] = v1;
}

// ---------------- fallback: fused naive fp32 (only if ws too small) ----------------
__global__ __launch_bounds__(256) void naive_kernel(const float* __restrict__ x,
                                                    const float* __restrict__ w,
                                                    const float* __restrict__ b,
                                                    float* __restrict__ out) {
    __shared__ float xs[D_IN];
    __shared__ float os[E_OUT];
    __shared__ float red[4];
    const int n = blockIdx.x;
    const float* xr = x + (size_t)n * D_IN;
    for (int i = threadIdx.x; i < D_IN; i += 256) xs[i] = xr[i];
    __syncthreads();
    for (int i = threadIdx.x; i < E_OUT; i += 256) {
        float s = b[i];
        const float* wr = w + (size_t)i * K_CONV;
        for (int k = 0; k < K_CONV; ++k) s += wr[k] * xs[i + k];
        os[i] = s;
    }
    __syncthreads();
    float ss = 0.0f;
    for (int i = threadIdx.x; i < E_OUT; i += 256) ss += os[i] * os[i];
#pragma unroll
    for (int off = 32; off > 0; off >>= 1) ss += __shfl_xor(ss, off, 64);
    if ((threadIdx.x & 63) == 0) red[threadIdx.x >> 6] = ss;
    __syncthreads();
    const float inv = 1.0f / fmaxf(sqrtf(red[0] + red[1] + red[2] + red[3]), EPS_N);
    float* orow = out + (size_t)n * E_OUT;
    for (int i = threadIdx.x; i < E_OUT; i += 256) orow[i] = os[i] * inv;
}

extern "C" void kernel_launch(void* const* d_in, const int* in_sizes, int n_in,
                              void* d_out, int out_size, void* d_ws, size_t ws_size,
                              hipStream_t stream) {
    const float* x = (const float*)d_in[0];
    const float* w = (const float*)d_in[1];
    const float* b = (const float*)d_in[2];
    float* out = (float*)d_out;

    const size_t wb_bytes  = (size_t)E_OUT * D_IN * sizeof(u16);   // 2 MiB
    const size_t psq_bytes = (size_t)4 * N_BATCH * sizeof(float);  // 256 KiB

    if (ws_size < wb_bytes + psq_bytes) {
        naive_kernel<<<N_BATCH, 256, 0, stream>>>(x, w, b, out);
        return;
    }

    u16*   wb  = (u16*)d_ws;
    float* Psq = (float*)((char*)d_ws + wb_bytes);

    prep_w_kernel<<<(E_OUT * D_IN) / 256, 256, 0, stream>>>(w, wb);

    gemm_fused_kernel<<<512, 256, 0, stream>>>(x, wb, b, out, Psq);

    norm_kernel<<<N_BATCH / 4, 256, 0, stream>>>(out, Psq);
}

// Round 4
// 235.110 us; speedup vs baseline: 1.2716x; 1.2716x over previous
//
#include <hip/hip_runtime.h>
#include <hip/hip_bf16.h>
#include <stdint.h>

#define N_BATCH 16384
#define D_IN    2048
#define E_OUT   512
#define K_CONV  1537   // D_IN - E_OUT + 1
#define EPS_N   1e-12f
#define BKD     64     // K-depth per tile
#define NT      32     // k-tiles over full [0, 2048)
#define ACT     25     // active tiles per 64-col quadrant (band union = 1600 k)

typedef unsigned short u16;
typedef __bf16 bf16x8 __attribute__((ext_vector_type(8)));
typedef float  f32x4  __attribute__((ext_vector_type(4)));

__device__ __forceinline__ unsigned f2bf_sw(float f) {
    union { float f; unsigned int u; } a; a.f = f;
    unsigned int r = a.u + 0x7FFFu + ((a.u >> 16) & 1u);   // RNE
    return r >> 16;
}

__device__ __forceinline__ unsigned pk_bf16(float a, float b) {
#if __has_builtin(__builtin_amdgcn_cvt_pk_bf16_f32)
    typedef __bf16 bf16x2 __attribute__((ext_vector_type(2)));
    bf16x2 r = __builtin_amdgcn_cvt_pk_bf16_f32(a, b);     // HW RNE, 1 inst / 2 elems
    union { bf16x2 v; unsigned u; } c; c.v = r;
    return c.u;
#else
    return f2bf_sw(a) | (f2bf_sw(b) << 16);
#endif
}

// ---------------- densify banded W into bf16 (E_OUT x D_IN) ----------------
__global__ __launch_bounds__(256) void prep_w_kernel(const float* __restrict__ w,
                                                     u16* __restrict__ wb) {
    int idx = blockIdx.x * 256 + threadIdx.x;
    int e = idx >> 11;
    int d = idx & (D_IN - 1);
    int k = d - e;
    float v = (k >= 0 && k < K_CONV) ? w[e * K_CONV + k] : 0.0f;
    wb[idx] = (u16)f2bf_sw(v);
}

// ---------------- ONE fused kernel: GEMM + bias + normalize + store ----------
// R3 lesson: ~150us of the 243us total was OUTSIDE the gemm (C round-trip +
// norm kernel + Psq + launch gaps) — structural, untouchable by gemm tuning.
// This kernel gives each block the ENTIRE output row-block (64 rows x all 512
// cols; grid=256=1/CU, 8 waves = 8 n-quadrants of 64 cols), so L2-normalize
// is block-local: acc+bias -> register ssq -> LDS reduce -> scale -> single
// final store. K walks the full [0,2048) in 32 tiles; wave q computes only
// tiles [q, q+25) (quadrant band union = 1600 k; out-of-band W is zero-filled
// so the skip is exact). Pipeline = the verified R2 structure: A reg-staged +
// cvt_pk + swizzled ds_write (A tile is tiny now: 2 f32x4/thread), B via
// global_load_lds with pre-swizzled source, double-buffered, counted vmcnt(2)
// barrier (drains the 8 B-glds, keeps the 2 A-loads in flight).
__global__ __launch_bounds__(512, 2) void fused_kernel(const float* __restrict__ A,
                                                       const u16* __restrict__ B,
                                                       const float* __restrict__ bias,
                                                       float* __restrict__ out) {
    __shared__ __align__(16) u16 Asb[2][64][64];    // 16 KB  (A k-tile, swizzled)
    __shared__ __align__(16) u16 Bsb[2][512][64];   // 128 KB (full-E B k-tile)
    __shared__ float ssq_lds[64];

    const int tid  = threadIdx.x;
    const int lane = tid & 63;
    const int wq   = tid >> 6;        // wave = n-quadrant (cols [64*wq, 64*wq+64))
    const int quad = lane >> 4;
    const int r16  = lane & 15;

    const int m0 = blockIdx.x * 64;

    // ---- A staging map: 1024 f32x4 chunks; thread holds chunks tid, tid+512
    //      (rows row, row+32 at the same c16) -> pack to bf16, swizzled ds_write
    const float* agA0;
    u16* asW0;                         // swizzled dest (buf0); +4096 u16 = buf1
    {
        const int row = tid >> 4;      // [0, 32)
        const int c16 = tid & 15;      // 16B f32 chunk within row
        agA0 = A + (size_t)(m0 + row) * D_IN + c16 * 4;
        const int byte0 = row * 128 + ((((c16 >> 1) ^ (row & 7)) << 4) | ((c16 & 1) << 3));
        asW0 = (u16*)((char*)&Asb[0][0][0] + byte0);
    }
    const float* agA1 = agA0 + (size_t)32 * D_IN;
    u16* asW1 = asW0 + 2048;           // +32 rows * 64 u16 = 4096 B

    // ---- B staging (glds): 4096 chunks, 8/thread; lane-linear dest,
    //      pre-swizzled source octet (sw = oct ^ e&7)
    const u16* bg[8];
    u16* bsD[8];
#pragma unroll
    for (int c = 0; c < 8; ++c) {
        const int li = tid + 512 * c;
        const int e  = li >> 3;
        const int oc = li & 7;
        const int sw = oc ^ (e & 7);
        bg[c]  = B + (size_t)e * D_IN + sw * 8;
        bsD[c] = &Bsb[0][0][0] + li * 8;
    }

    // ---- fragment read bases (swizzled, buf0); +i*1024 u16 walks 16-row frags
    const int sx = r16 & 7;
    const u16* aF[2];
    const u16* bF[2];
#pragma unroll
    for (int kk = 0; kk < 2; ++kk) {
        aF[kk] = &Asb[0][0][0] + r16 * 64 + ((((kk * 4) + quad) ^ sx) << 3);
        bF[kk] = &Bsb[0][0][0] + (wq * 64 + r16) * 64 + ((((kk * 4) + quad) ^ sx) << 3);
    }

    f32x4 acc[4][4] = {};
    f32x4 arE[2], arO[2];

#define LOAD_AF(dst)                                            \
    dst[0] = *(const f32x4*)agA0;                               \
    dst[1] = *(const f32x4*)agA1;                               \
    agA0 += BKD; agA1 += BKD;

#define PACK_A(src, buf)                                        \
    {                                                           \
        uint2 o0, o1;                                           \
        o0.x = pk_bf16(src[0][0], src[0][1]);                   \
        o0.y = pk_bf16(src[0][2], src[0][3]);                   \
        o1.x = pk_bf16(src[1][0], src[1][1]);                   \
        o1.y = pk_bf16(src[1][2], src[1][3]);                   \
        *(uint2*)(asW0 + (buf) * 4096) = o0;                    \
        *(uint2*)(asW1 + (buf) * 4096) = o1;                    \
    }

#define GLDS_B(buf)                                             \
    _Pragma("unroll")                                           \
    for (int c = 0; c < 8; ++c)                                 \
        __builtin_amdgcn_global_load_lds(                       \
            (const __attribute__((address_space(1))) void*)bg[c], \
            (__attribute__((address_space(3))) void*)(bsD[c] + (buf) * 32768), 16, 0, 0);

#define BUMP_B()                                                \
    _Pragma("unroll")                                           \
    for (int c = 0; c < 8; ++c) bg[c] += BKD;

#define COMPUTE(buf, t)                                         \
    if ((t) >= wq && (t) < wq + ACT) {                          \
        _Pragma("unroll")                                       \
        for (int kk = 0; kk < 2; ++kk) {                        \
            bf16x8 af[4], bf[4];                                \
            _Pragma("unroll")                                   \
            for (int i = 0; i < 4; ++i)                         \
                af[i] = *(const bf16x8*)(aF[kk] + (buf) * 4096 + i * 1024); \
            _Pragma("unroll")                                   \
            for (int j = 0; j < 4; ++j)                         \
                bf[j] = *(const bf16x8*)(bF[kk] + (buf) * 32768 + j * 1024); \
            _Pragma("unroll")                                   \
            for (int i = 0; i < 4; ++i)                         \
                _Pragma("unroll")                                \
                for (int j = 0; j < 4; ++j)                     \
                    acc[i][j] = __builtin_amdgcn_mfma_f32_16x16x32_bf16(af[i], bf[j], acc[i][j], 0, 0, 0); \
        }                                                       \
    }

// drain this iter's 8 B-glds (oldest), keep the 2 A-loads in flight;
// lgkmcnt(0) fences the PACK ds_writes before the barrier.
#define BAR_FAST()                                              \
    __builtin_amdgcn_sched_barrier(0);                          \
    asm volatile("s_waitcnt vmcnt(2) lgkmcnt(0)");              \
    __builtin_amdgcn_sched_barrier(0);                          \
    __builtin_amdgcn_s_barrier();                               \
    __builtin_amdgcn_sched_barrier(0);

    // ---- prologue: tile0 staged to buf0; tile1 A-regs prefetched ----
    {
        f32x4 arT[2];
        LOAD_AF(arT);                  // tile 0
        LOAD_AF(arO);                  // tile 1 (in flight)
        GLDS_B(0);                     // B tile 0 -> buf0
        BUMP_B();
        PACK_A(arT, 0);
        __syncthreads();               // one-time full drain
    }

    // ---- main loop: 15 double-iterations, tiles 0..29 ----
    for (int p = 0; p < 15; ++p) {
        {   // even iter t = 2p: compute buf0; stage tile t+1 -> buf1
            const int t = 2 * p;
            GLDS_B(1);
            BUMP_B();
            LOAD_AF(arE);              // tile t+2
            PACK_A(arO, 1);            // tile t+1 (regs from last iter)
            COMPUTE(0, t);
            BAR_FAST();
        }
        {   // odd iter t = 2p+1: compute buf1; stage tile t+1 -> buf0
            const int t = 2 * p + 1;
            GLDS_B(0);
            BUMP_B();
            LOAD_AF(arO);              // tile t+2
            PACK_A(arE, 0);            // tile t+1
            COMPUTE(1, t);
            BAR_FAST();
        }
    }

    // ---- tail: tiles 30, 31 ----
    {
        GLDS_B(1);                     // B tile 31 -> buf1
        PACK_A(arO, 1);                // A tile 31 (regs loaded at t=29)
        COMPUTE(0, 30);
        __syncthreads();               // full drain
        COMPUTE(1, 31);
    }

    // ---- fused epilogue: bias, row-ssq reduce, normalize, single store ----
    __syncthreads();
    if (tid < 64) ssq_lds[tid] = 0.0f;

    float bv[4];
#pragma unroll
    for (int j = 0; j < 4; ++j) bv[j] = bias[wq * 64 + j * 16 + r16];

    __syncthreads();

    float ssq_t[16];
#pragma unroll
    for (int t = 0; t < 16; ++t) ssq_t[t] = 0.0f;

#pragma unroll
    for (int j = 0; j < 4; ++j)
#pragma unroll
        for (int i = 0; i < 4; ++i)
#pragma unroll
            for (int rg = 0; rg < 4; ++rg) {
                const float v = acc[i][j][rg] + bv[j];
                acc[i][j][rg] = v;
                ssq_t[i * 4 + rg] += v * v;
            }

#pragma unroll
    for (int off = 1; off <= 8; off <<= 1)
#pragma unroll
        for (int t = 0; t < 16; ++t)
            ssq_t[t] += __shfl_xor(ssq_t[t], off, 64);

    if (r16 == 0) {
#pragma unroll
        for (int i = 0; i < 4; ++i)
#pragma unroll
            for (int rg = 0; rg < 4; ++rg)
                atomicAdd(&ssq_lds[i * 16 + quad * 4 + rg], ssq_t[i * 4 + rg]);
    }
    __syncthreads();
    if (tid < 64) ssq_lds[tid] = 1.0f / fmaxf(sqrtf(ssq_lds[tid]), EPS_N);
    __syncthreads();

#pragma unroll
    for (int i = 0; i < 4; ++i)
#pragma unroll
        for (int rg = 0; rg < 4; ++rg) {
            const int rl = i * 16 + quad * 4 + rg;
            const float inv = ssq_lds[rl];
            float* orow = out + (size_t)(m0 + rl) * E_OUT + wq * 64 + r16;
#pragma unroll
            for (int j = 0; j < 4; ++j)
                orow[j * 16] = acc[i][j][rg] * inv;
        }
}

// ---------------- fallback: fused naive fp32 (only if ws too small) ----------------
__global__ __launch_bounds__(256) void naive_kernel(const float* __restrict__ x,
                                                    const float* __restrict__ w,
                                                    const float* __restrict__ b,
                                                    float* __restrict__ out) {
    __shared__ float xs[D_IN];
    __shared__ float os[E_OUT];
    __shared__ float red[4];
    const int n = blockIdx.x;
    const float* xr = x + (size_t)n * D_IN;
    for (int i = threadIdx.x; i < D_IN; i += 256) xs[i] = xr[i];
    __syncthreads();
    for (int i = threadIdx.x; i < E_OUT; i += 256) {
        float s = b[i];
        const float* wr = w + (size_t)i * K_CONV;
        for (int k = 0; k < K_CONV; ++k) s += wr[k] * xs[i + k];
        os[i] = s;
    }
    __syncthreads();
    float ss = 0.0f;
    for (int i = threadIdx.x; i < E_OUT; i += 256) ss += os[i] * os[i];
#pragma unroll
    for (int off = 32; off > 0; off >>= 1) ss += __shfl_xor(ss, off, 64);
    if ((threadIdx.x & 63) == 0) red[threadIdx.x >> 6] = ss;
    __syncthreads();
    const float inv = 1.0f / fmaxf(sqrtf(red[0] + red[1] + red[2] + red[3]), EPS_N);
    float* orow = out + (size_t)n * E_OUT;
    for (int i = threadIdx.x; i < E_OUT; i += 256) orow[i] = os[i] * inv;
}

extern "C" void kernel_launch(void* const* d_in, const int* in_sizes, int n_in,
                              void* d_out, int out_size, void* d_ws, size_t ws_size,
                              hipStream_t stream) {
    const float* x = (const float*)d_in[0];
    const float* w = (const float*)d_in[1];
    const float* b = (const float*)d_in[2];
    float* out = (float*)d_out;

    const size_t wb_bytes = (size_t)E_OUT * D_IN * sizeof(u16);   // 2 MiB

    if (ws_size < wb_bytes) {
        naive_kernel<<<N_BATCH, 256, 0, stream>>>(x, w, b, out);
        return;
    }

    u16* wb = (u16*)d_ws;

    prep_w_kernel<<<(E_OUT * D_IN) / 256, 256, 0, stream>>>(w, wb);

    fused_kernel<<<N_BATCH / 64, 512, 0, stream>>>(x, wb, b, out);
}